// Round 4
// baseline (29032.318 us; speedup 1.0000x reference)
//
#include <hip/hip_runtime.h>

// AlphatRNN B=128,T=512,D=256,H=1024,L=2,O=1 — bf16 MFMA persistent kernel, R4.
// R4: (1) barriers scoped to 8 independent 32-WG groups (state row-block mg is
// group-local); (2) software-pipelined partials: each staged LDS span feeds two
// GEMMs (current phase + a partial for a later phase), so per step only 3
// serialized stage->barrier chains remain and phase A is MFMA-free; (3) reduce
// buffer stored as 4 scalar planes (bank-conflict-free).

typedef unsigned short u16;
typedef unsigned long long u64;
typedef __attribute__((ext_vector_type(8))) short short8;
typedef __attribute__((ext_vector_type(4))) float f32x4;

#define NB   128
#define TT   512
#define DD   256
#define HH   1024
#define NWG  256
#define NTHR 512
#define SPAN (NB * HH)
#define GSIZE 32            // WGs per sync group (same-mg)

// ---- ws layout (bytes) ----
#define S0_OFF  0u          // bf16 [2][128][1024]
#define S1_OFF  524288u     // bf16 [2][128][1024]
#define H0_OFF  1048576u    // bf16 [128][1024]
#define CTR_OFF 1310720u    // 16384 u32 group-barrier counters (1536 barids x 8 groups)
#define W_OFF   1376256u    // bf16 weights: 6x[1024][1024], then [1024][256]x2
#define NBIG    6291456u    // 6 * 1048576

__device__ __forceinline__ u16 f2bf(float f) {   // RNE, finite inputs only
    unsigned u = __builtin_bit_cast(unsigned, f);
    return (u16)((u + 0x7fffu + ((u >> 16) & 1u)) >> 16);
}

__device__ __forceinline__ u64 agent_load64(const u64* p) {
    return __hip_atomic_load(p, __ATOMIC_RELAXED, __HIP_MEMORY_SCOPE_AGENT);
}
__device__ __forceinline__ void agent_store16(u16* p, u16 v) {
    __hip_atomic_store(p, v, __ATOMIC_RELAXED, __HIP_MEMORY_SCOPE_AGENT);
}

// 32-WG group barrier: fresh counter per (instance, group); memset each launch.
// Leading __syncthreads drains all waves' sc1 stores (vmcnt0) before arrival.
__device__ __forceinline__ void gbar(unsigned* ctr, int mg, int& barid)
{
    __syncthreads();
    if (threadIdx.x == 0) {
        unsigned* c = ctr + (barid << 3) + mg;
        __hip_atomic_fetch_add(c, 1u, __ATOMIC_RELEASE, __HIP_MEMORY_SCOPE_AGENT);
        while (__hip_atomic_load(c, __ATOMIC_RELAXED, __HIP_MEMORY_SCOPE_AGENT) != GSIZE)
            __builtin_amdgcn_s_sleep(1);
    }
    ++barid;
    __syncthreads();
}

// stage one 16-row bf16 span slice [16][1024] into LDS (stride 2048B, XOR-swizzled)
__device__ __forceinline__ void stage_span(char* dst, const u16* src, int m0, int tid)
{
    const u64* s64 = (const u64*)src;
    #pragma unroll
    for (int i = 0; i < 8; ++i) {
        int idx = tid + (i << 9);
        int row = idx >> 8, ch = idx & 255;              // 256 x 8B chunks per row
        u64 v = agent_load64(s64 + ((size_t)(m0 + row) << 8) + ch);
        *(u64*)(dst + row * 2048 + ((ch << 3) ^ ((row & 7) << 4))) = v;
    }
}

// stage x_t [16][256] fp32 -> bf16 LDS (stride 512B, swizzled)
__device__ __forceinline__ void stage_x(char* dst, const float* x, int m0, int t, int tid)
{
    int row = tid >> 5, e0 = (tid & 31) << 3;
    const float* p = x + (((size_t)(m0 + row) * TT + t) << 8) + e0;
    float4 a = *(const float4*)p;
    float4 b = *(const float4*)(p + 4);
    short8 v;
    v[0] = (short)f2bf(a.x); v[1] = (short)f2bf(a.y); v[2] = (short)f2bf(a.z); v[3] = (short)f2bf(a.w);
    v[4] = (short)f2bf(b.x); v[5] = (short)f2bf(b.y); v[6] = (short)f2bf(b.z); v[7] = (short)f2bf(b.w);
    *(short8*)(dst + row * 512 + ((e0 << 1) ^ ((row & 7) << 4))) = v;
}

// one K-span of S[16xK] @ W[n..n+16, K]^T via builtin mfma 16x16x32.
template<int NS>
__device__ __forceinline__ f32x4 mm(f32x4 acc, const char* A, int astride,
                                    const u16* W, int K, int wr, int ks0,
                                    int lrow, int lkg)
{
    const int rs = (lrow & 7) << 4;
    const char* ar = A + lrow * astride;
    const u16*  wp = W + (size_t)wr * K + ks0 * 32 + lkg * 8;
    #pragma unroll
    for (int s = 0; s < NS; ++s) {
        short8 a = *(const short8*)(ar + ((((ks0 + s) << 6) + (lkg << 4)) ^ rs));
        short8 b = *(const short8*)(wp + s * 32);
        acc = __builtin_amdgcn_mfma_f32_16x16x32_bf16(a, b, acc, 0, 0, 0);
    }
    return acc;
}

// fold 4 K-quarter partials into kq==0 waves. Scalar planes: 4B lane stride,
// conflict-free. Leading sync protects red WAR across phases.
__device__ __forceinline__ f32x4 wgreduce(f32x4 acc, int nt, int kq, int lane,
                                          float (*red)[3][2][64])
{
    __syncthreads();
    if (kq) {
        #pragma unroll
        for (int c = 0; c < 4; ++c) red[c][kq - 1][nt][lane] = acc[c];
    }
    __syncthreads();
    if (!kq) {
        #pragma unroll
        for (int c = 0; c < 4; ++c)
            acc[c] += red[c][0][nt][lane] + red[c][1][nt][lane] + red[c][2][nt][lane];
    }
    return acc;
}

__global__ void conv_weights(const float* Uas0, const float* Whh0, const float* Wax1,
                             const float* Uas1, const float* Wih1, const float* Whh1,
                             const float* Wax0, const float* Wih0, u16* dst)
{
    for (size_t i = (size_t)blockIdx.x * blockDim.x + threadIdx.x; i < 6815744u;
         i += (size_t)gridDim.x * blockDim.x) {
        const float* src; size_t off;
        if (i < NBIG) {
            int seg = (int)(i >> 20); off = i & 1048575u;
            src = seg == 0 ? Uas0 : seg == 1 ? Whh0 : seg == 2 ? Wax1
                : seg == 3 ? Uas1 : seg == 4 ? Wih1 : Whh1;
        } else {
            size_t j = i - NBIG; off = j & 262143u;
            src = (j >> 18) ? Wih0 : Wax0;
        }
        dst[i] = f2bf(src[off]);
    }
}

extern "C" __global__ void __launch_bounds__(NTHR, 1)
alphat_mfma(const float* __restrict__ x,
            const u16* __restrict__ wUas0, const u16* __restrict__ wWhh0,
            const u16* __restrict__ wWax1, const u16* __restrict__ wUas1,
            const u16* __restrict__ wWih1, const u16* __restrict__ wWhh1,
            const u16* __restrict__ wWax0, const u16* __restrict__ wWih0,
            const float* __restrict__ ba0, const float* __restrict__ bh0,
            const float* __restrict__ ba1, const float* __restrict__ bh1,
            const float* __restrict__ fcW, const float* __restrict__ fcb,
            float* __restrict__ out,
            u16* s0b, u16* s1b, u16* h0b, unsigned* ctr)
{
    __shared__ alignas(16) char sS[16 * 2048];   // 32 KB span buffer
    __shared__ alignas(16) char sX[16 * 512];    //  8 KB x_t buffer
    __shared__ float red[4][3][2][64];           //  6 KB reduce planes

    const int tid  = threadIdx.x;
    const int wv   = tid >> 6;
    const int lane = tid & 63;
    const int nt   = wv & 1;          // n-tile 0/1
    const int kq   = wv >> 1;         // K-quarter 0..3
    const int lrow = lane & 15;
    const int lkg  = lane >> 4;

    // XCD swizzle: same-XCD WGs (wg&7) share 4 n-groups -> weights L2-hot
    const int wg = blockIdx.x;
    const int ng = (wg & 7) * 4 + ((wg >> 3) & 3);
    const int mg = wg >> 5;           // sync-group id = batch row-block
    const int m0 = mg * 16;
    const int n0 = ng * 32;

    const int wr    = n0 + nt * 16 + lrow;   // B-frag weight row
    const int gcol  = n0 + nt * 16 + lrow;   // owned C col
    const int grow0 = m0 + lkg * 4;          // owned C rows base

    const float vba0 = ba0[gcol], vbh0 = bh0[gcol];
    const float vba1 = ba1[gcol], vbh1 = bh1[gcol];

    float h0l[4] = {0,0,0,0}, s0l[4] = {0,0,0,0};
    float h1l[4] = {0,0,0,0}, s1l[4] = {0,0,0,0};
    int barid = 0;

    // ---- prologue: x_0 partials; state partials start at 0 ----
    stage_x(sX, x, m0, 0, tid);
    __syncthreads();
    f32x4 pAx = {0.f,0.f,0.f,0.f}, pBx = {0.f,0.f,0.f,0.f};
    pAx = mm<2>(pAx, sX, 512, wWax0, DD, wr, kq * 2, lrow, lkg);
    pBx = mm<2>(pBx, sX, 512, wWih0, DD, wr, kq * 2, lrow, lkg);
    f32x4 pAs = {0.f,0.f,0.f,0.f};   // s0@Uas0 partial (from prev B-stage)
    f32x4 pC1 = {0.f,0.f,0.f,0.f};   // s1@Uas1 partial (from prev D-stage)

    for (int t = 0; t < TT; ++t) {
        const int cur = t & 1;
        u16* s0nxt = s0b + (cur ^ 1) * SPAN;
        u16* s1nxt = s1b + (cur ^ 1) * SPAN;

        // ---- A: alpha0 = sig(pAx + pAs + ba0); s0' = a*h0+(1-a)*s0  [no staging]
        f32x4 acc = pAx + pAs;
        acc = wgreduce(acc, nt, kq, lane, red);
        if (wv < 2) {
            #pragma unroll
            for (int r = 0; r < 4; ++r) {
                float u  = acc[r] + vba0;
                float al = 1.f / (1.f + __expf(-u));
                float sn = al * h0l[r] + (1.f - al) * s0l[r];
                s0l[r] = sn;
                agent_store16(s0nxt + (size_t)(grow0 + r) * HH + gcol, f2bf(sn));
            }
        }
        gbar(ctr, mg, barid);

        // ---- B: h0 = tanh(pBx + s0'@Whh0 + bh0); also pAs = s0'@Uas0 for t+1
        stage_span(sS, s0nxt, m0, tid);
        __syncthreads();
        acc = pBx;
        acc = mm<8>(acc, sS, 2048, wWhh0, HH, wr, kq * 8, lrow, lkg);
        pAs = f32x4{0.f,0.f,0.f,0.f};
        pAs = mm<8>(pAs, sS, 2048, wUas0, HH, wr, kq * 8, lrow, lkg);
        acc = wgreduce(acc, nt, kq, lane, red);
        if (wv < 2) {
            #pragma unroll
            for (int r = 0; r < 4; ++r) {
                float hn = tanhf(acc[r] + vbh0);
                h0l[r] = hn;
                agent_store16(h0b + (size_t)(grow0 + r) * HH + gcol, f2bf(hn));
            }
        }
        gbar(ctr, mg, barid);

        // ---- C: alpha1 = sig(pC1 + h0@Wax1 + ba1); also pD1 = h0@Wih1
        stage_span(sS, h0b, m0, tid);
        __syncthreads();
        acc = pC1;
        acc = mm<8>(acc, sS, 2048, wWax1, HH, wr, kq * 8, lrow, lkg);
        f32x4 pD1 = {0.f,0.f,0.f,0.f};
        pD1 = mm<8>(pD1, sS, 2048, wWih1, HH, wr, kq * 8, lrow, lkg);
        acc = wgreduce(acc, nt, kq, lane, red);
        if (wv < 2) {
            #pragma unroll
            for (int r = 0; r < 4; ++r) {
                float u  = acc[r] + vba1;
                float al = 1.f / (1.f + __expf(-u));
                float sn = al * h1l[r] + (1.f - al) * s1l[r];
                s1l[r] = sn;
                agent_store16(s1nxt + (size_t)(grow0 + r) * HH + gcol, f2bf(sn));
            }
        }
        gbar(ctr, mg, barid);

        // ---- D: h1 = tanh(pD1 + s1'@Whh1 + bh1); also pC1 = s1'@Uas1 and
        //         x_{t+1} partials for next step. No trailing barrier needed.
        stage_span(sS, s1nxt, m0, tid);
        const bool pf = (t + 1 < TT);
        if (pf) stage_x(sX, x, m0, t + 1, tid);
        __syncthreads();
        acc = pD1;
        acc = mm<8>(acc, sS, 2048, wWhh1, HH, wr, kq * 8, lrow, lkg);
        pC1 = f32x4{0.f,0.f,0.f,0.f};
        pC1 = mm<8>(pC1, sS, 2048, wUas1, HH, wr, kq * 8, lrow, lkg);
        if (pf) {
            pAx = f32x4{0.f,0.f,0.f,0.f};
            pAx = mm<2>(pAx, sX, 512, wWax0, DD, wr, kq * 2, lrow, lkg);
            pBx = f32x4{0.f,0.f,0.f,0.f};
            pBx = mm<2>(pBx, sX, 512, wWih0, DD, wr, kq * 2, lrow, lkg);
        }
        acc = wgreduce(acc, nt, kq, lane, red);
        if (wv < 2) {
            #pragma unroll
            for (int r = 0; r < 4; ++r) h1l[r] = tanhf(acc[r] + vbh1);
        }
        // next A's wgreduce leading sync protects red; slot WAR windows all
        // span >=1 group barrier (readers pass barA(t+1) before writer A(t+2)).
    }

    // ---- epilogue ----
    if (wv < 2) {
        const size_t HIDB = NB, SMOB = NB + 2 * (size_t)SPAN;
        #pragma unroll
        for (int r = 0; r < 4; ++r) {
            size_t o = (size_t)(grow0 + r) * HH + gcol;
            out[HIDB + o]        = h0l[r];
            out[HIDB + SPAN + o] = h1l[r];
            out[SMOB + o]        = s0l[r];
            out[SMOB + SPAN + o] = s1l[r];
        }
        #pragma unroll
        for (int r = 0; r < 4; ++r) {
            float v = h1l[r] * fcW[gcol];
            v += __shfl_xor(v, 1); v += __shfl_xor(v, 2);
            v += __shfl_xor(v, 4); v += __shfl_xor(v, 8);
            if (lrow == 0) {
                if (ng == 0 && nt == 0) v += fcb[0];
                atomicAdd(out + grow0 + r, v);
            }
        }
    }
}

extern "C" void kernel_launch(void* const* d_in, const int* in_sizes, int n_in,
                              void* d_out, int out_size, void* d_ws, size_t ws_size,
                              hipStream_t stream)
{
    const float* x    = (const float*)d_in[0];
    const float* Wax0 = (const float*)d_in[1];
    const float* Uas0 = (const float*)d_in[2];
    const float* ba0  = (const float*)d_in[3];
    const float* Wih0 = (const float*)d_in[4];
    const float* Whh0 = (const float*)d_in[5];
    const float* bh0  = (const float*)d_in[6];
    const float* Wax1 = (const float*)d_in[7];
    const float* Uas1 = (const float*)d_in[8];
    const float* ba1  = (const float*)d_in[9];
    const float* Wih1 = (const float*)d_in[10];
    const float* Whh1 = (const float*)d_in[11];
    const float* bh1  = (const float*)d_in[12];
    const float* fcW  = (const float*)d_in[13];
    const float* fcb  = (const float*)d_in[14];
    float* out = (float*)d_out;

    char* ws = (char*)d_ws;
    u16* s0b = (u16*)(ws + S0_OFF);
    u16* s1b = (u16*)(ws + S1_OFF);
    u16* h0b = (u16*)(ws + H0_OFF);
    unsigned* ctr = (unsigned*)(ws + CTR_OFF);
    u16* wbase = (u16*)(ws + W_OFF);
    u16* wUas0 = wbase + 0 * 1048576;
    u16* wWhh0 = wbase + 1 * 1048576;
    u16* wWax1 = wbase + 2 * 1048576;
    u16* wUas1 = wbase + 3 * 1048576;
    u16* wWih1 = wbase + 4 * 1048576;
    u16* wWhh1 = wbase + 5 * 1048576;
    u16* wWax0 = wbase + 6 * 1048576;
    u16* wWih0 = wbase + 6 * 1048576 + 262144;

    // zero state spans + barrier counters + output (accumulated via atomics)
    hipMemsetAsync(d_ws, 0, W_OFF, stream);
    hipMemsetAsync(d_out, 0, (size_t)out_size * sizeof(float), stream);

    conv_weights<<<dim3(1024), dim3(256), 0, stream>>>(
        Uas0, Whh0, Wax1, Uas1, Wih1, Whh1, Wax0, Wih0, wbase);

    alphat_mfma<<<dim3(NWG), dim3(NTHR), 0, stream>>>(
        x, wUas0, wWhh0, wWax1, wUas1, wWih1, wWhh1, wWax0, wWih0,
        ba0, bh0, ba1, bh1, fcW, fcb, out, s0b, s1b, h0b, ctr);
}

// Round 5
// 25732.272 us; speedup vs baseline: 1.1282x; 1.1282x over previous
//
#include <hip/hip_runtime.h>

// AlphatRNN B=128,T=512,D=256,H=1024,L=2,O=1 — bf16 MFMA persistent kernel, R5.
// R5 = R4 pipelined dataflow + GLOBAL 256-WG barrier (revert R4's group scoping,
// isolating it as the regression variable) + 256B-padded barrier counters +
// conflict-free scalar-plane reduce. Single-buffered state spans (all producer->
// consumer->next-producer windows span >=1 global barrier).

typedef unsigned short u16;
typedef unsigned long long u64;
typedef __attribute__((ext_vector_type(8))) short short8;
typedef __attribute__((ext_vector_type(4))) float f32x4;

#define NB   128
#define TT   512
#define DD   256
#define HH   1024
#define NWG  256
#define NTHR 512
#define SPAN (NB * HH)

// ---- ws layout (bytes) ----
#define S0_OFF  0u          // bf16 [128][1024] (single buffer)
#define S1_OFF  262144u     // bf16 [128][1024]
#define H0_OFF  524288u     // bf16 [128][1024]
#define CTR_OFF 786432u     // 1536 barrier counters, 256B apart (393216 B)
#define W_OFF   1179648u    // bf16 weights: 6x[1024][1024], then [1024][256]x2
#define NBIG    6291456u    // 6 * 1048576

__device__ __forceinline__ u16 f2bf(float f) {   // RNE, finite inputs only
    unsigned u = __builtin_bit_cast(unsigned, f);
    return (u16)((u + 0x7fffu + ((u >> 16) & 1u)) >> 16);
}

__device__ __forceinline__ u64 agent_load64(const u64* p) {
    return __hip_atomic_load(p, __ATOMIC_RELAXED, __HIP_MEMORY_SCOPE_AGENT);
}
__device__ __forceinline__ void agent_store16(u16* p, u16 v) {
    __hip_atomic_store(p, v, __ATOMIC_RELAXED, __HIP_MEMORY_SCOPE_AGENT);
}

// Global 256-WG barrier; one 256B-padded counter per instance (no line sharing
// between consecutive barids). Leading __syncthreads drains sc1 stores.
__device__ __forceinline__ void gbar(unsigned* ctr, int& barid)
{
    __syncthreads();
    if (threadIdx.x == 0) {
        unsigned* c = ctr + (barid << 6);
        __hip_atomic_fetch_add(c, 1u, __ATOMIC_RELEASE, __HIP_MEMORY_SCOPE_AGENT);
        while (__hip_atomic_load(c, __ATOMIC_RELAXED, __HIP_MEMORY_SCOPE_AGENT) != NWG)
            __builtin_amdgcn_s_sleep(1);
    }
    ++barid;
    __syncthreads();
}

// stage one 16-row bf16 span slice [16][1024] into LDS (stride 2048B, XOR-swizzled)
__device__ __forceinline__ void stage_span(char* dst, const u16* src, int m0, int tid)
{
    const u64* s64 = (const u64*)src;
    #pragma unroll
    for (int i = 0; i < 8; ++i) {
        int idx = tid + (i << 9);
        int row = idx >> 8, ch = idx & 255;              // 256 x 8B chunks per row
        u64 v = agent_load64(s64 + ((size_t)(m0 + row) << 8) + ch);
        *(u64*)(dst + row * 2048 + ((ch << 3) ^ ((row & 7) << 4))) = v;
    }
}

// stage x_t [16][256] fp32 -> bf16 LDS (stride 512B, swizzled)
__device__ __forceinline__ void stage_x(char* dst, const float* x, int m0, int t, int tid)
{
    int row = tid >> 5, e0 = (tid & 31) << 3;
    const float* p = x + (((size_t)(m0 + row) * TT + t) << 8) + e0;
    float4 a = *(const float4*)p;
    float4 b = *(const float4*)(p + 4);
    short8 v;
    v[0] = (short)f2bf(a.x); v[1] = (short)f2bf(a.y); v[2] = (short)f2bf(a.z); v[3] = (short)f2bf(a.w);
    v[4] = (short)f2bf(b.x); v[5] = (short)f2bf(b.y); v[6] = (short)f2bf(b.z); v[7] = (short)f2bf(b.w);
    *(short8*)(dst + row * 512 + ((e0 << 1) ^ ((row & 7) << 4))) = v;
}

// one K-span of S[16xK] @ W[n..n+16, K]^T via builtin mfma 16x16x32.
template<int NS>
__device__ __forceinline__ f32x4 mm(f32x4 acc, const char* A, int astride,
                                    const u16* W, int K, int wr, int ks0,
                                    int lrow, int lkg)
{
    const int rs = (lrow & 7) << 4;
    const char* ar = A + lrow * astride;
    const u16*  wp = W + (size_t)wr * K + ks0 * 32 + lkg * 8;
    #pragma unroll
    for (int s = 0; s < NS; ++s) {
        short8 a = *(const short8*)(ar + ((((ks0 + s) << 6) + (lkg << 4)) ^ rs));
        short8 b = *(const short8*)(wp + s * 32);
        acc = __builtin_amdgcn_mfma_f32_16x16x32_bf16(a, b, acc, 0, 0, 0);
    }
    return acc;
}

// fold 4 K-quarter partials into kq==0 waves. Scalar planes (4B lane stride,
// conflict-free); R3 protocol: store -> sync -> read. Cross-phase red WAR is
// ordered by the gbar/syncthreads that precedes every subsequent write.
__device__ __forceinline__ f32x4 wgreduce(f32x4 acc, int nt, int kq, int lane,
                                          float (*red)[3][2][64])
{
    if (kq) {
        #pragma unroll
        for (int c = 0; c < 4; ++c) red[c][kq - 1][nt][lane] = acc[c];
    }
    __syncthreads();
    if (!kq) {
        #pragma unroll
        for (int c = 0; c < 4; ++c)
            acc[c] += red[c][0][nt][lane] + red[c][1][nt][lane] + red[c][2][nt][lane];
    }
    return acc;
}

__global__ void conv_weights(const float* Uas0, const float* Whh0, const float* Wax1,
                             const float* Uas1, const float* Wih1, const float* Whh1,
                             const float* Wax0, const float* Wih0, u16* dst)
{
    for (size_t i = (size_t)blockIdx.x * blockDim.x + threadIdx.x; i < 6815744u;
         i += (size_t)gridDim.x * blockDim.x) {
        const float* src; size_t off;
        if (i < NBIG) {
            int seg = (int)(i >> 20); off = i & 1048575u;
            src = seg == 0 ? Uas0 : seg == 1 ? Whh0 : seg == 2 ? Wax1
                : seg == 3 ? Uas1 : seg == 4 ? Wih1 : Whh1;
        } else {
            size_t j = i - NBIG; off = j & 262143u;
            src = (j >> 18) ? Wih0 : Wax0;
        }
        dst[i] = f2bf(src[off]);
    }
}

extern "C" __global__ void __launch_bounds__(NTHR, 1)
alphat_mfma(const float* __restrict__ x,
            const u16* __restrict__ wUas0, const u16* __restrict__ wWhh0,
            const u16* __restrict__ wWax1, const u16* __restrict__ wUas1,
            const u16* __restrict__ wWih1, const u16* __restrict__ wWhh1,
            const u16* __restrict__ wWax0, const u16* __restrict__ wWih0,
            const float* __restrict__ ba0, const float* __restrict__ bh0,
            const float* __restrict__ ba1, const float* __restrict__ bh1,
            const float* __restrict__ fcW, const float* __restrict__ fcb,
            float* __restrict__ out,
            u16* s0b, u16* s1b, u16* h0b, unsigned* ctr)
{
    __shared__ alignas(16) char sS[16 * 2048];   // 32 KB span buffer
    __shared__ alignas(16) char sX[16 * 512];    //  8 KB x_t buffer
    __shared__ float red[4][3][2][64];           //  6 KB reduce planes

    const int tid  = threadIdx.x;
    const int wv   = tid >> 6;
    const int lane = tid & 63;
    const int nt   = wv & 1;          // n-tile 0/1
    const int kq   = wv >> 1;         // K-quarter 0..3
    const int lrow = lane & 15;
    const int lkg  = lane >> 4;

    // XCD swizzle: same-XCD WGs (wg&7) share 4 n-groups -> weights L2-hot
    const int wg = blockIdx.x;
    const int ng = (wg & 7) * 4 + ((wg >> 3) & 3);
    const int mg = wg >> 5;
    const int m0 = mg * 16;
    const int n0 = ng * 32;

    const int wr    = n0 + nt * 16 + lrow;   // B-frag weight row
    const int gcol  = n0 + nt * 16 + lrow;   // owned C col
    const int grow0 = m0 + lkg * 4;          // owned C rows base

    const float vba0 = ba0[gcol], vbh0 = bh0[gcol];
    const float vba1 = ba1[gcol], vbh1 = bh1[gcol];

    float h0l[4] = {0,0,0,0}, s0l[4] = {0,0,0,0};
    float h1l[4] = {0,0,0,0}, s1l[4] = {0,0,0,0};
    int barid = 0;

    // ---- prologue: x_0 partials; state partials start at 0 (s0=s1=0) ----
    stage_x(sX, x, m0, 0, tid);
    __syncthreads();
    f32x4 pAx = {0.f,0.f,0.f,0.f}, pBx = {0.f,0.f,0.f,0.f};
    pAx = mm<2>(pAx, sX, 512, wWax0, DD, wr, kq * 2, lrow, lkg);
    pBx = mm<2>(pBx, sX, 512, wWih0, DD, wr, kq * 2, lrow, lkg);
    f32x4 pAs = {0.f,0.f,0.f,0.f};   // s0@Uas0 partial (computed in B-stage)
    f32x4 pC1 = {0.f,0.f,0.f,0.f};   // s1@Uas1 partial (computed in D-stage)

    for (int t = 0; t < TT; ++t) {
        // ---- A: alpha0 = sig(pAx + pAs + ba0); s0' = a*h0+(1-a)*s0  [no staging]
        __syncthreads();   // red WAR: D(t-1) kq0-readers vs A kq-writers
        f32x4 acc = pAx + pAs;
        acc = wgreduce(acc, nt, kq, lane, red);
        if (wv < 2) {
            #pragma unroll
            for (int r = 0; r < 4; ++r) {
                float u  = acc[r] + vba0;
                float al = 1.f / (1.f + __expf(-u));
                float sn = al * h0l[r] + (1.f - al) * s0l[r];
                s0l[r] = sn;
                agent_store16(s0b + (size_t)(grow0 + r) * HH + gcol, f2bf(sn));
            }
        }
        gbar(ctr, barid);

        // ---- B: h0 = tanh(pBx + s0'@Whh0 + bh0); also pAs = s0'@Uas0 for t+1
        stage_span(sS, s0b, m0, tid);
        __syncthreads();
        acc = pBx;
        acc = mm<8>(acc, sS, 2048, wWhh0, HH, wr, kq * 8, lrow, lkg);
        pAs = f32x4{0.f,0.f,0.f,0.f};
        pAs = mm<8>(pAs, sS, 2048, wUas0, HH, wr, kq * 8, lrow, lkg);
        acc = wgreduce(acc, nt, kq, lane, red);
        if (wv < 2) {
            #pragma unroll
            for (int r = 0; r < 4; ++r) {
                float hn = tanhf(acc[r] + vbh0);
                h0l[r] = hn;
                agent_store16(h0b + (size_t)(grow0 + r) * HH + gcol, f2bf(hn));
            }
        }
        gbar(ctr, barid);

        // ---- C: alpha1 = sig(pC1 + h0@Wax1 + ba1); also pD1 = h0@Wih1
        stage_span(sS, h0b, m0, tid);
        __syncthreads();
        acc = pC1;
        acc = mm<8>(acc, sS, 2048, wWax1, HH, wr, kq * 8, lrow, lkg);
        f32x4 pD1 = {0.f,0.f,0.f,0.f};
        pD1 = mm<8>(pD1, sS, 2048, wWih1, HH, wr, kq * 8, lrow, lkg);
        acc = wgreduce(acc, nt, kq, lane, red);
        if (wv < 2) {
            #pragma unroll
            for (int r = 0; r < 4; ++r) {
                float u  = acc[r] + vba1;
                float al = 1.f / (1.f + __expf(-u));
                float sn = al * h1l[r] + (1.f - al) * s1l[r];
                s1l[r] = sn;
                agent_store16(s1b + (size_t)(grow0 + r) * HH + gcol, f2bf(sn));
            }
        }
        gbar(ctr, barid);

        // ---- D: h1 = tanh(pD1 + s1'@Whh1 + bh1); also pC1 = s1'@Uas1 and
        //         x_{t+1} partials. No trailing barrier (A's sync + gbarA cover).
        stage_span(sS, s1b, m0, tid);
        const bool pf = (t + 1 < TT);
        if (pf) stage_x(sX, x, m0, t + 1, tid);
        __syncthreads();
        acc = pD1;
        acc = mm<8>(acc, sS, 2048, wWhh1, HH, wr, kq * 8, lrow, lkg);
        pC1 = f32x4{0.f,0.f,0.f,0.f};
        pC1 = mm<8>(pC1, sS, 2048, wUas1, HH, wr, kq * 8, lrow, lkg);
        if (pf) {
            pAx = f32x4{0.f,0.f,0.f,0.f};
            pAx = mm<2>(pAx, sX, 512, wWax0, DD, wr, kq * 2, lrow, lkg);
            pBx = f32x4{0.f,0.f,0.f,0.f};
            pBx = mm<2>(pBx, sX, 512, wWih0, DD, wr, kq * 2, lrow, lkg);
        }
        acc = wgreduce(acc, nt, kq, lane, red);
        if (wv < 2) {
            #pragma unroll
            for (int r = 0; r < 4; ++r) h1l[r] = tanhf(acc[r] + vbh1);
        }
    }

    // ---- epilogue ----
    if (wv < 2) {
        const size_t HIDB = NB, SMOB = NB + 2 * (size_t)SPAN;
        #pragma unroll
        for (int r = 0; r < 4; ++r) {
            size_t o = (size_t)(grow0 + r) * HH + gcol;
            out[HIDB + o]        = h0l[r];
            out[HIDB + SPAN + o] = h1l[r];
            out[SMOB + o]        = s0l[r];
            out[SMOB + SPAN + o] = s1l[r];
        }
        #pragma unroll
        for (int r = 0; r < 4; ++r) {
            float v = h1l[r] * fcW[gcol];
            v += __shfl_xor(v, 1); v += __shfl_xor(v, 2);
            v += __shfl_xor(v, 4); v += __shfl_xor(v, 8);
            if (lrow == 0) {
                if (ng == 0 && nt == 0) v += fcb[0];
                atomicAdd(out + grow0 + r, v);
            }
        }
    }
}

extern "C" void kernel_launch(void* const* d_in, const int* in_sizes, int n_in,
                              void* d_out, int out_size, void* d_ws, size_t ws_size,
                              hipStream_t stream)
{
    const float* x    = (const float*)d_in[0];
    const float* Wax0 = (const float*)d_in[1];
    const float* Uas0 = (const float*)d_in[2];
    const float* ba0  = (const float*)d_in[3];
    const float* Wih0 = (const float*)d_in[4];
    const float* Whh0 = (const float*)d_in[5];
    const float* bh0  = (const float*)d_in[6];
    const float* Wax1 = (const float*)d_in[7];
    const float* Uas1 = (const float*)d_in[8];
    const float* ba1  = (const float*)d_in[9];
    const float* Wih1 = (const float*)d_in[10];
    const float* Whh1 = (const float*)d_in[11];
    const float* bh1  = (const float*)d_in[12];
    const float* fcW  = (const float*)d_in[13];
    const float* fcb  = (const float*)d_in[14];
    float* out = (float*)d_out;

    char* ws = (char*)d_ws;
    u16* s0b = (u16*)(ws + S0_OFF);
    u16* s1b = (u16*)(ws + S1_OFF);
    u16* h0b = (u16*)(ws + H0_OFF);
    unsigned* ctr = (unsigned*)(ws + CTR_OFF);
    u16* wbase = (u16*)(ws + W_OFF);
    u16* wUas0 = wbase + 0 * 1048576;
    u16* wWhh0 = wbase + 1 * 1048576;
    u16* wWax1 = wbase + 2 * 1048576;
    u16* wUas1 = wbase + 3 * 1048576;
    u16* wWih1 = wbase + 4 * 1048576;
    u16* wWhh1 = wbase + 5 * 1048576;
    u16* wWax0 = wbase + 6 * 1048576;
    u16* wWih0 = wbase + 6 * 1048576 + 262144;

    // zero state spans + barrier counters + output (accumulated via atomics)
    hipMemsetAsync(d_ws, 0, W_OFF, stream);
    hipMemsetAsync(d_out, 0, (size_t)out_size * sizeof(float), stream);

    conv_weights<<<dim3(1024), dim3(256), 0, stream>>>(
        Uas0, Whh0, Wax1, Uas1, Wih1, Whh1, Wax0, Wih0, wbase);

    alphat_mfma<<<dim3(NWG), dim3(NTHR), 0, stream>>>(
        x, wUas0, wWhh0, wWax1, wUas1, wWih1, wWhh1, wWax0, wWih0,
        ba0, bh0, ba1, bh1, fcW, fcb, out, s0b, s1b, h0b, ctr);
}

// Round 6
// 22888.405 us; speedup vs baseline: 1.2684x; 1.1242x over previous
//
#include <hip/hip_runtime.h>

// AlphatRNN B=128,T=512,D=256,H=1024,L=2,O=1 — bf16 MFMA persistent kernel, R6.
// R6: (1) phase A eliminated -> 2 barriers/step (B publishes h0(t) AND s0(t+1));
// (2) hierarchical 16x16 grid barrier (padded counters + broadcast flag);
// (3) NO LDS staging: MFMA A-frags load directly global->regs (agent scope);
// D prefetches next B's s0 frags. LDS = 12KB reduce planes only.

typedef unsigned short u16;
typedef unsigned long long u64;
typedef __attribute__((ext_vector_type(8))) short short8;
typedef __attribute__((ext_vector_type(4))) float f32x4;

#define NB   128
#define TT   512
#define DD   256
#define HH   1024
#define NWG  256
#define NTHR 512
#define SPAN (NB * HH)

// ---- ws layout (bytes) ----
#define S0_OFF  0u          // bf16 [2][128][1024] (parity double buffer)
#define S1_OFF  524288u     // bf16 [128][1024]
#define H0_OFF  786432u     // bf16 [128][1024]
#define CTR_OFF 1048576u    // 1032 barrier instances x 2304 B
#define W_OFF   3426304u    // bf16 weights: 6x[1024][1024], then [1024][256]x2
#define NBIG    6291456u    // 6 * 1048576

__device__ __forceinline__ u16 f2bf(float f) {   // RNE, finite inputs only
    unsigned u = __builtin_bit_cast(unsigned, f);
    return (u16)((u + 0x7fffu + ((u >> 16) & 1u)) >> 16);
}

__device__ __forceinline__ u64 agent_load64(const u64* p) {
    return __hip_atomic_load(p, __ATOMIC_RELAXED, __HIP_MEMORY_SCOPE_AGENT);
}
__device__ __forceinline__ void agent_store16(u16* p, u16 v) {
    __hip_atomic_store(p, v, __ATOMIC_RELAXED, __HIP_MEMORY_SCOPE_AGENT);
}

// Hierarchical 256-WG barrier: 16 group ctrs (128B apart) -> root -> flag.
// Fresh instance per barid (memset each launch). Leading __syncthreads drains
// all waves' sc1 stores before arrival; all counters live at L3 (coherent).
__device__ __forceinline__ void gbar(char* cb, int wg, int& barid)
{
    __syncthreads();
    if (threadIdx.x == 0) {
        char* base = cb + (size_t)barid * 2304;
        unsigned* grp  = (unsigned*)(base + ((wg >> 4) << 7));
        unsigned* root = (unsigned*)(base + 2048);
        unsigned* flag = (unsigned*)(base + 2176);
        if (__hip_atomic_fetch_add(grp, 1u, __ATOMIC_RELEASE,
                                   __HIP_MEMORY_SCOPE_AGENT) == 15u) {
            if (__hip_atomic_fetch_add(root, 1u, __ATOMIC_RELEASE,
                                       __HIP_MEMORY_SCOPE_AGENT) == 15u)
                __hip_atomic_store(flag, 1u, __ATOMIC_RELEASE,
                                   __HIP_MEMORY_SCOPE_AGENT);
        }
        while (!__hip_atomic_load(flag, __ATOMIC_ACQUIRE, __HIP_MEMORY_SCOPE_AGENT))
            __builtin_amdgcn_s_sleep(1);
    }
    ++barid;
    __syncthreads();
}

// load 8 A-frag short8's (one K-quarter of 16 rows) straight from a published
// bf16 span: lane(lrow,lkg) reads rows m0+lrow, k = kq*256 + s*32 + lkg*8.
__device__ __forceinline__ void load_frags(short8* fr, const u16* base,
                                           int row, int kq, int lkg)
{
    const u16* sp = base + ((size_t)row << 10) + kq * 256 + lkg * 8;
    #pragma unroll
    for (int s = 0; s < 8; ++s) {
        union { short8 v; u64 q[2]; } u_;
        u_.q[0] = agent_load64((const u64*)(sp + s * 32));
        u_.q[1] = agent_load64((const u64*)(sp + s * 32 + 4));
        fr[s] = u_.v;
    }
}

// acc += S(frags) @ W[wr, kq-quarter]^T  (K=1024, 8 slices of 32)
template<int NS>
__device__ __forceinline__ f32x4 mm_reg(f32x4 acc, const short8* fr, const u16* W,
                                        int wr, int kq, int lkg)
{
    const u16* wp = W + ((size_t)wr << 10) + kq * 256 + lkg * 8;
    #pragma unroll
    for (int s = 0; s < NS; ++s)
        acc = __builtin_amdgcn_mfma_f32_16x16x32_bf16(
            fr[s], *(const short8*)(wp + s * 32), acc, 0, 0, 0);
    return acc;
}

// acc += x_t(fp32, reg-convert) @ Wx[wr, kq-quarter]^T  (K=256, 2 slices)
__device__ __forceinline__ f32x4 mm_x(f32x4 acc, const float* xrow, const u16* W,
                                      int wr, int kq, int lkg)
{
    #pragma unroll
    for (int s = 0; s < 2; ++s) {
        const float* p = xrow + kq * 64 + s * 32 + lkg * 8;
        float4 a = *(const float4*)p;
        float4 b = *(const float4*)(p + 4);
        short8 v;
        v[0]=(short)f2bf(a.x); v[1]=(short)f2bf(a.y); v[2]=(short)f2bf(a.z); v[3]=(short)f2bf(a.w);
        v[4]=(short)f2bf(b.x); v[5]=(short)f2bf(b.y); v[6]=(short)f2bf(b.z); v[7]=(short)f2bf(b.w);
        const u16* wp = W + ((size_t)wr << 8) + kq * 64 + s * 32 + lkg * 8;
        acc = __builtin_amdgcn_mfma_f32_16x16x32_bf16(
            v, *(const short8*)wp, acc, 0, 0, 0);
    }
    return acc;
}

// K-quarter reduce planes: 4B lane stride, conflict-free.
__device__ __forceinline__ void red_put(float (*red)[3][2][64], int p, f32x4 v,
                                        int nt, int kq, int lane)
{
    if (kq) {
        #pragma unroll
        for (int c = 0; c < 4; ++c) red[p + c][kq - 1][nt][lane] = v[c];
    }
}
__device__ __forceinline__ f32x4 red_get(float (*red)[3][2][64], int p, f32x4 v,
                                         int nt, int lane)
{
    #pragma unroll
    for (int c = 0; c < 4; ++c)
        v[c] += red[p + c][0][nt][lane] + red[p + c][1][nt][lane]
              + red[p + c][2][nt][lane];
    return v;
}

__global__ void conv_weights(const float* Uas0, const float* Whh0, const float* Wax1,
                             const float* Uas1, const float* Wih1, const float* Whh1,
                             const float* Wax0, const float* Wih0, u16* dst)
{
    for (size_t i = (size_t)blockIdx.x * blockDim.x + threadIdx.x; i < 6815744u;
         i += (size_t)gridDim.x * blockDim.x) {
        const float* src; size_t off;
        if (i < NBIG) {
            int seg = (int)(i >> 20); off = i & 1048575u;
            src = seg == 0 ? Uas0 : seg == 1 ? Whh0 : seg == 2 ? Wax1
                : seg == 3 ? Uas1 : seg == 4 ? Wih1 : Whh1;
        } else {
            size_t j = i - NBIG; off = j & 262143u;
            src = (j >> 18) ? Wih0 : Wax0;
        }
        dst[i] = f2bf(src[off]);
    }
}

extern "C" __global__ void __launch_bounds__(NTHR, 1)
alphat_mfma(const float* __restrict__ x,
            const u16* __restrict__ wUas0, const u16* __restrict__ wWhh0,
            const u16* __restrict__ wWax1, const u16* __restrict__ wUas1,
            const u16* __restrict__ wWih1, const u16* __restrict__ wWhh1,
            const u16* __restrict__ wWax0, const u16* __restrict__ wWih0,
            const float* __restrict__ ba0, const float* __restrict__ bh0,
            const float* __restrict__ ba1, const float* __restrict__ bh1,
            const float* __restrict__ fcW, const float* __restrict__ fcb,
            float* __restrict__ out,
            u16* s0b, u16* s1b, u16* h0b, char* cbase)
{
    __shared__ float red[8][3][2][64];           // 12 KB reduce planes (only LDS)

    const int tid  = threadIdx.x;
    const int wv   = tid >> 6;
    const int lane = tid & 63;
    const int nt   = wv & 1;          // n-tile 0/1
    const int kq   = wv >> 1;         // K-quarter 0..3
    const int lrow = lane & 15;
    const int lkg  = lane >> 4;

    // XCD swizzle: same-XCD WGs (wg&7) share 4 n-groups -> weights L2-hot
    const int wg = blockIdx.x;
    const int ng = (wg & 7) * 4 + ((wg >> 3) & 3);
    const int mg = wg >> 5;
    const int m0 = mg * 16;
    const int n0 = ng * 32;

    const int wr    = n0 + nt * 16 + lrow;   // B-frag weight row
    const int gcol  = n0 + nt * 16 + lrow;   // owned C col
    const int grow0 = m0 + lkg * 4;          // owned C rows base
    const int arow  = m0 + lrow;             // A-frag source row

    const float vba0 = ba0[gcol], vbh0 = bh0[gcol];
    const float vba1 = ba1[gcol], vbh1 = bh1[gcol];

    const f32x4 zf = {0.f, 0.f, 0.f, 0.f};
    float h0l[4] = {0,0,0,0}, s0l[4] = {0,0,0,0};
    float h1l[4] = {0,0,0,0}, s1l[4] = {0,0,0,0};
    int barid = 0;

    // ---- prologue: s0(0)=0 -> frags zero; x partials for t=0 (B) and t=1 (alpha0)
    short8 frags[8];
    #pragma unroll
    for (int s = 0; s < 8; ++s)
        #pragma unroll
        for (int i = 0; i < 8; ++i) frags[s][i] = 0;
    const float* xbase = x + (size_t)arow * (TT * DD);
    f32x4 pBx  = mm_x(zf, xbase + 0 * DD, wWih0, wr, kq, lkg);   // Wih0 x_0
    f32x4 pAxN = mm_x(zf, xbase + 1 * DD, wWax0, wr, kq, lkg);   // Wax0 x_1
    f32x4 pC1  = zf;                                             // Uas1 s1(-1)=0

    for (int t = 0; t < TT; ++t) {
        u16* s0nxt = s0b + ((t + 1) & 1) * SPAN;

        // ---- B: h0(t)=tanh(pBx + Whh0 s0(t) + bh0); alpha0(t+1)=sig(pAxN +
        //      Uas0 s0(t) + ba0); s0(t+1)=a*h0(t)+(1-a)*s0(t). Publish both.
        __syncthreads();   // red WAR vs D(t-1) kq0-readers
        f32x4 acc = mm_reg<8>(pBx,  frags, wWhh0, wr, kq, lkg);
        f32x4 pA  = mm_reg<8>(pAxN, frags, wUas0, wr, kq, lkg);
        red_put(red, 0, acc, nt, kq, lane);
        red_put(red, 4, pA,  nt, kq, lane);
        __syncthreads();
        if (wv < 2) {
            acc = red_get(red, 0, acc, nt, lane);
            pA  = red_get(red, 4, pA,  nt, lane);
            #pragma unroll
            for (int r = 0; r < 4; ++r) {
                float hn = tanhf(acc[r] + vbh0);
                agent_store16(h0b + (size_t)(grow0 + r) * HH + gcol, f2bf(hn));
                if (t + 1 < TT) {
                    float al = 1.f / (1.f + __expf(-(pA[r] + vba0)));
                    float sn = al * hn + (1.f - al) * s0l[r];
                    s0l[r] = sn;
                    agent_store16(s0nxt + (size_t)(grow0 + r) * HH + gcol, f2bf(sn));
                }
                h0l[r] = hn;
            }
        }
        gbar(cbase, wg, barid);

        // ---- C: alpha1(t)=sig(pC1 + Wax1 h0(t) + ba1); s1(t)=a1*h1(t-1)+(1-a1)*s1(t-1)
        //      Also pD1 = Wih1 h0(t) (stays partial; reduced in D).
        short8 fh[8];
        load_frags(fh, h0b, arow, kq, lkg);
        acc = mm_reg<8>(pC1, fh, wWax1, wr, kq, lkg);
        f32x4 pD1 = mm_reg<8>(zf, fh, wWih1, wr, kq, lkg);
        red_put(red, 0, acc, nt, kq, lane);
        __syncthreads();
        if (wv < 2) {
            acc = red_get(red, 0, acc, nt, lane);
            #pragma unroll
            for (int r = 0; r < 4; ++r) {
                float al = 1.f / (1.f + __expf(-(acc[r] + vba1)));
                float sn = al * h1l[r] + (1.f - al) * s1l[r];
                s1l[r] = sn;
                agent_store16(s1b + (size_t)(grow0 + r) * HH + gcol, f2bf(sn));
            }
        }
        gbar(cbase, wg, barid);

        // ---- D: h1(t)=tanh(pD1 + Whh1 s1(t) + bh1). Also: pC1=Uas1 s1(t) for
        //      C(t+1); prefetch s0(t+1) frags for B(t+1); x partials for t+1/t+2.
        short8 fs1[8];
        load_frags(fs1, s1b, arow, kq, lkg);
        if (t + 1 < TT) load_frags(frags, s0nxt, arow, kq, lkg);
        acc = mm_reg<8>(pD1, fs1, wWhh1, wr, kq, lkg);
        pC1 = mm_reg<8>(zf,  fs1, wUas1, wr, kq, lkg);
        if (t + 1 < TT) pBx  = mm_x(zf, xbase + (size_t)(t + 1) * DD, wWih0, wr, kq, lkg);
        if (t + 2 < TT) pAxN = mm_x(zf, xbase + (size_t)(t + 2) * DD, wWax0, wr, kq, lkg);
        red_put(red, 0, acc, nt, kq, lane);
        __syncthreads();
        if (wv < 2) {
            acc = red_get(red, 0, acc, nt, lane);
            #pragma unroll
            for (int r = 0; r < 4; ++r) h1l[r] = tanhf(acc[r] + vbh1);
        }
        // no barrier: B(t+1) leading __syncthreads covers red WAR; buffer
        // windows all span >=1 gbar (s0 parity-double-buffered).
    }

    // ---- epilogue ----
    if (wv < 2) {
        const size_t HIDB = NB, SMOB = NB + 2 * (size_t)SPAN;
        #pragma unroll
        for (int r = 0; r < 4; ++r) {
            size_t o = (size_t)(grow0 + r) * HH + gcol;
            out[HIDB + o]        = h0l[r];
            out[HIDB + SPAN + o] = h1l[r];
            out[SMOB + o]        = s0l[r];
            out[SMOB + SPAN + o] = s1l[r];
        }
        #pragma unroll
        for (int r = 0; r < 4; ++r) {
            float v = h1l[r] * fcW[gcol];
            v += __shfl_xor(v, 1); v += __shfl_xor(v, 2);
            v += __shfl_xor(v, 4); v += __shfl_xor(v, 8);
            if (lrow == 0) {
                if (ng == 0 && nt == 0) v += fcb[0];
                atomicAdd(out + grow0 + r, v);
            }
        }
    }
}

extern "C" void kernel_launch(void* const* d_in, const int* in_sizes, int n_in,
                              void* d_out, int out_size, void* d_ws, size_t ws_size,
                              hipStream_t stream)
{
    const float* x    = (const float*)d_in[0];
    const float* Wax0 = (const float*)d_in[1];
    const float* Uas0 = (const float*)d_in[2];
    const float* ba0  = (const float*)d_in[3];
    const float* Wih0 = (const float*)d_in[4];
    const float* Whh0 = (const float*)d_in[5];
    const float* bh0  = (const float*)d_in[6];
    const float* Wax1 = (const float*)d_in[7];
    const float* Uas1 = (const float*)d_in[8];
    const float* ba1  = (const float*)d_in[9];
    const float* Wih1 = (const float*)d_in[10];
    const float* Whh1 = (const float*)d_in[11];
    const float* bh1  = (const float*)d_in[12];
    const float* fcW  = (const float*)d_in[13];
    const float* fcb  = (const float*)d_in[14];
    float* out = (float*)d_out;

    char* ws = (char*)d_ws;
    u16* s0b = (u16*)(ws + S0_OFF);
    u16* s1b = (u16*)(ws + S1_OFF);
    u16* h0b = (u16*)(ws + H0_OFF);
    char* cbase = ws + CTR_OFF;
    u16* wbase = (u16*)(ws + W_OFF);
    u16* wUas0 = wbase + 0 * 1048576;
    u16* wWhh0 = wbase + 1 * 1048576;
    u16* wWax1 = wbase + 2 * 1048576;
    u16* wUas1 = wbase + 3 * 1048576;
    u16* wWih1 = wbase + 4 * 1048576;
    u16* wWhh1 = wbase + 5 * 1048576;
    u16* wWax0 = wbase + 6 * 1048576;
    u16* wWih0 = wbase + 6 * 1048576 + 262144;

    // zero state spans + barrier counters + output (accumulated via atomics)
    hipMemsetAsync(d_ws, 0, W_OFF, stream);
    hipMemsetAsync(d_out, 0, (size_t)out_size * sizeof(float), stream);

    conv_weights<<<dim3(1024), dim3(256), 0, stream>>>(
        Uas0, Whh0, Wax1, Uas1, Wih1, Whh1, Wax0, Wih0, wbase);

    alphat_mfma<<<dim3(NWG), dim3(NTHR), 0, stream>>>(
        x, wUas0, wWhh0, wWax1, wUas1, wWih1, wWhh1, wWax0, wWih0,
        ba0, bh0, ba1, bh1, fcW, fcb, out, s0b, s1b, h0b, cbase);
}